// Round 7
// baseline (184.314 us; speedup 1.0000x reference)
//
#include <hip/hip_runtime.h>

typedef unsigned short u16;
typedef unsigned int u32;

typedef __bf16 bf16x8 __attribute__((ext_vector_type(8)));
typedef float floatx4 __attribute__((ext_vector_type(4)));

// ---- helpers ----------------------------------------------------------------

__device__ __forceinline__ u32 f2bf_rne(float f) {
    // round-to-nearest-even fp32 -> bf16 (bit pattern in low 16)
    u32 u = __builtin_bit_cast(u32, f);
    return (u + 0x7fffu + ((u >> 16) & 1u)) >> 16;
}

__device__ __forceinline__ u32 pack_bf2(float lo, float hi) {
    // round-half-up fp32 pair -> packed bf16x2 (cheaper than RNE, same 0.5-ulp bound)
    u32 a = __builtin_bit_cast(u32, lo) + 0x8000u;
    u32 b = __builtin_bit_cast(u32, hi) + 0x8000u;
    return (a >> 16) | (b & 0xffff0000u);
}

__device__ __forceinline__ float quant_w(float x) {
    // WAGE Quantize.W, BITS_W=2: clip to [-0.5,0.5], round to grid step 0.5 (RNE)
    float xc = fminf(fmaxf(x, -0.5f), 0.5f);
    return rintf(xc * 2.0f) * 0.5f;
}

__device__ __forceinline__ void gload_lds16(const u16* g, u16* l) {
    __builtin_amdgcn_global_load_lds(
        (const __attribute__((address_space(1))) void*)g,
        (__attribute__((address_space(3))) void*)l,
        16, 0, 0);
}

// ---- kernel 1: quantize + transpose W[k][n] -> Bt[n][k] bf16 ----------------

__global__ __launch_bounds__(256) void quantW_kernel(const float* __restrict__ W,
                                                     u16* __restrict__ Bt) {
    __shared__ u16 tile[32][33];
    const int KN = 1024;
    const int tid = threadIdx.x;
    int b = blockIdx.x;          // 0..1023
    int n0 = (b & 31) * 32;
    int k0 = (b >> 5) * 32;
    int tx = tid & 31;           // 0..31
    int ty = tid >> 5;           // 0..7
#pragma unroll
    for (int i = 0; i < 4; i++) {
        int kl = ty + i * 8;
        float x = W[(k0 + kl) * KN + n0 + tx];
        tile[kl][tx] = (u16)f2bf_rne(quant_w(x));
    }
    __syncthreads();
#pragma unroll
    for (int i = 0; i < 4; i++) {
        int nl = ty + i * 8;
        Bt[(n0 + nl) * KN + k0 + tx] = tile[tx][nl];
    }
}

// ---- kernel 2: C = A_f32 * Bt^T with fused A cast (bf16 MFMA, fp32 out) -----
// r2's proven loop shape (BK=64, 128x128, 4 waves, 2-barrier) with the A-cast
// fused in: per iter each thread loads 8x float4 of fp32 A (register-prefetched
// during the PREVIOUS compute phase, so the barrier drain finds them landed),
// packs to bf16, ds_write_b128 into the same swizzled LDS layout r2 proved
// conflict-free. B stays global_load_lds. Eliminates the 96 MB A-cast
// round-trip and the ~20 us prep-A pass.

__global__ __launch_bounds__(256) void gemm_fused_kernel(const float* __restrict__ A,
                                                         const u16* __restrict__ Bt,
                                                         float* __restrict__ C) {
    const int K = 1024;
    const int N = 1024;

    __shared__ alignas(16) u16 As[128 * 64];  // 16 KB bf16
    __shared__ alignas(16) u16 Bs[128 * 64];  // 16 KB

    const int tid = threadIdx.x;
    const int mbase = blockIdx.x * 128;   // x = M: XCD (id%8) gets L2-resident slice
    const int nbase = blockIdx.y * 128;
    const int lane = tid & 63;
    const int wv = tid >> 6;
    const int wm = (wv & 1) * 64;
    const int wn = (wv >> 1) * 64;
    const int frow = lane & 15;           // m (or n) index within 16-tile
    const int fkc = lane >> 4;            // k-chunk (0..3) within a 32-wide k-half
    const int rsw = frow & 7;             // XOR bank-swizzle key (reader side)

    // ---- A staging (fused cast): thread t covers row r = t>>1, k-half h = t&1
    const int ar = tid >> 1;              // 0..127
    const int ah = tid & 1;               // 0..1
    const float* Aga = &A[(size_t)(mbase + ar) * K + ah * 32];
    // LDS: global chunk g (16B of bf16) of row r goes to position g ^ (r&7)
    u16* AsRow = &As[ar * 64];
    const int asw = ar & 7;

    // ---- B staging: identical to r2 (global_load_lds, g8 swizzle)
    const int srow = tid >> 3;
    const int g8 = (tid & 7) ^ (srow & 7);
    const u16* Bga[4];
#pragma unroll
    for (int q = 0; q < 4; q++)
        Bga[q] = &Bt[(size_t)(nbase + q * 32 + srow) * K + g8 * 8];

    floatx4 acc[4][4] = {};

    // prologue: prefetch A fp32 for tile 0
    floatx4 pf[8];
#pragma unroll
    for (int j = 0; j < 8; j++) pf[j] = *(const floatx4*)&Aga[j * 4];

#pragma unroll 1
    for (int kt = 0; kt < K; kt += 64) {
        __syncthreads();  // prior compute's LDS reads done; drains prefetch A loads (covered)
        // stage B tile kt via DMA
#pragma unroll
        for (int q = 0; q < 4; q++)
            gload_lds16(Bga[q] + kt, &Bs[(q * 256 + tid) * 8]);
        // convert + write prefetched A tile kt
#pragma unroll
        for (int j2 = 0; j2 < 4; j2++) {
            uint4 o;
            o.x = pack_bf2(pf[2 * j2].x, pf[2 * j2].y);
            o.y = pack_bf2(pf[2 * j2].z, pf[2 * j2].w);
            o.z = pack_bf2(pf[2 * j2 + 1].x, pf[2 * j2 + 1].y);
            o.w = pack_bf2(pf[2 * j2 + 1].z, pf[2 * j2 + 1].w);
            int p = (ah * 4 + j2) ^ asw;  // swizzled chunk position
            *(uint4*)&AsRow[p * 8] = o;
        }
        __syncthreads();  // drains B DMA (only 4 loads; cvt VALU as partial cover)

        // prefetch A fp32 for tile kt+64 DURING compute: drained at next
        // iteration's first barrier, i.e. with a full compute phase of cover.
        if (kt + 64 < K) {
#pragma unroll
            for (int j = 0; j < 8; j++) pf[j] = *(const floatx4*)&Aga[kt + 64 + j * 4];
        }

#pragma unroll
        for (int s = 0; s < 2; s++) {
            bf16x8 af[4], bf[4];
#pragma unroll
            for (int i = 0; i < 4; i++)
                af[i] = *(const bf16x8*)&As[(wm + i * 16 + frow) * 64 +
                                            (((s * 4 + fkc) ^ rsw) * 8)];
#pragma unroll
            for (int j = 0; j < 4; j++)
                bf[j] = *(const bf16x8*)&Bs[(wn + j * 16 + frow) * 64 +
                                            (((s * 4 + fkc) ^ rsw) * 8)];
#pragma unroll
            for (int i = 0; i < 4; i++)
#pragma unroll
                for (int j = 0; j < 4; j++)
                    acc[i][j] = __builtin_amdgcn_mfma_f32_16x16x32_bf16(
                        af[i], bf[j], acc[i][j], 0, 0, 0);
        }
    }

    // epilogue: C/D layout col = lane&15, row = (lane>>4)*4 + reg
    const int crow = (lane >> 4) * 4;
    const int ccol = lane & 15;
#pragma unroll
    for (int i = 0; i < 4; i++) {
#pragma unroll
        for (int j = 0; j < 4; j++) {
            float* cp = &C[(size_t)(mbase + wm + i * 16 + crow) * N + nbase + wn + j * 16 + ccol];
#pragma unroll
            for (int r = 0; r < 4; r++) cp[r * N] = acc[i][j][r];
        }
    }
}

// ---- launch -----------------------------------------------------------------

extern "C" void kernel_launch(void* const* d_in, const int* in_sizes, int n_in,
                              void* d_out, int out_size, void* d_ws, size_t ws_size,
                              hipStream_t stream) {
    const float* A = (const float*)d_in[0];   // 16384 x 1024
    const float* W = (const float*)d_in[1];   // 1024 x 1024
    float* C = (float*)d_out;                 // 16384 x 1024

    u16* Btq = (u16*)d_ws;                    // 2 MB: quantized W^T (bf16)

    quantW_kernel<<<1024, 256, 0, stream>>>(W, Btq);
    gemm_fused_kernel<<<dim3(128, 8), 256, 0, stream>>>(A, Btq, C);
}